// Round 1
// baseline (190.119 us; speedup 1.0000x reference)
//
#include <hip/hip_runtime.h>
#include <stdint.h>

#define P_DIM 256
#define NREF  4096
#define NIN   8192
#define DF    512

typedef __bf16 bf16x8 __attribute__((ext_vector_type(8)));
typedef float  f32x4  __attribute__((ext_vector_type(4)));

static __device__ __forceinline__ unsigned short f2bf(float f) {
    // round-to-nearest-even fp32 -> bf16 (inputs are finite normals)
    uint32_t u = __builtin_bit_cast(uint32_t, f);
    u += 0x7FFFu + ((u >> 16) & 1u);
    return (unsigned short)(u >> 16);
}

__global__ void cast_f32_bf16(const float* __restrict__ src,
                              unsigned short* __restrict__ dst, int n4) {
    int i = blockIdx.x * blockDim.x + threadIdx.x;
    int stride = gridDim.x * blockDim.x;
    const float4* s4 = (const float4*)src;
    ushort4* d4 = (ushort4*)dst;
    for (; i < n4; i += stride) {
        float4 v = s4[i];
        ushort4 o;
        o.x = f2bf(v.x); o.y = f2bf(v.y); o.z = f2bf(v.z); o.w = f2bf(v.w);
        d4[i] = o;
    }
}

// C = A @ B^T with A[M,Kd], B[N,Kd] bf16 row-major (both K-contiguous).
// SQMASK: C[m,n] = (ZA[m]==ZB[n]) ? dot^2 : 0, stored bf16.
// else:   C[m,n] = dot, stored fp32.
// BK=64 bf16 = 128B/row; LDS chunk index XOR-swizzled by (row&7) so
// ds_read_b128 column reads spread over 8 bank groups (2-way = free).
template <int BM, int BN, int WR, int WC, bool SQMASK>
__global__ __launch_bounds__(256) void gemm_bt(
    const unsigned short* __restrict__ A,
    const unsigned short* __restrict__ B,
    void* __restrict__ Cp,
    const int* __restrict__ ZA,
    const int* __restrict__ ZB,
    int M, int N, int Kd)
{
    constexpr int BK = 64;
    constexpr int RT = BM / WR / 16;
    constexpr int CT = BN / WC / 16;
    __shared__ unsigned short tA[BM * BK];
    __shared__ unsigned short tB[BN * BK];

    const int tid  = threadIdx.x;
    const int wave = tid >> 6;
    const int lane = tid & 63;
    const int wr = wave / WC, wc = wave % WC;
    const int m0 = blockIdx.y * BM, n0 = blockIdx.x * BN;
    const int waveM = wr * (BM / WR), waveN = wc * (BN / WC);
    const int lrow = lane >> 3, ls = lane & 7;   // staging: 8 rows x 8 chunks
    const int l15 = lane & 15, lq = lane >> 4;   // mfma fragment coords

    f32x4 acc[RT][CT];
#pragma unroll
    for (int r = 0; r < RT; ++r)
#pragma unroll
        for (int c = 0; c < CT; ++c)
            acc[r][c] = (f32x4){0.f, 0.f, 0.f, 0.f};

    constexpr int TOTAL_CB = (BM + BN) / 8;   // 1KB staging calls per K-step
    constexpr int CB_PER_WAVE = TOTAL_CB / 4;

    for (int k0 = 0; k0 < Kd; k0 += BK) {
        __syncthreads();   // prior compute done before LDS overwrite
#pragma unroll
        for (int it = 0; it < CB_PER_WAVE; ++it) {
            int cb = wave + it * 4;
            bool isB = (cb >= BM / 8);
            int cb2 = isB ? cb - BM / 8 : cb;
            int row = cb2 * 8 + lrow;
            int g = ls ^ (row & 7);    // global chunk feeding LDS slot ls
            const unsigned short* gp = (isB ? B : A)
                + (size_t)((isB ? n0 : m0) + row) * Kd + (size_t)(k0 + g * 8);
            unsigned short* lp = (isB ? tB : tA) + cb2 * (8 * BK); // wave-uniform
            __builtin_amdgcn_global_load_lds(
                (const __attribute__((address_space(1))) void*)gp,
                (__attribute__((address_space(3))) void*)lp,
                16, 0, 0);
        }
        __syncthreads();   // drains vmcnt before compute
#pragma unroll
        for (int kk = 0; kk < BK; kk += 32) {
            const int cbase = kk >> 3;
            bf16x8 af[RT], bfr[CT];
#pragma unroll
            for (int r = 0; r < RT; ++r) {
                int m = waveM + r * 16 + l15;
                int ch = (cbase + lq) ^ (m & 7);
                af[r] = *(const bf16x8*)&tA[m * BK + ch * 8];
            }
#pragma unroll
            for (int c = 0; c < CT; ++c) {
                int n = waveN + c * 16 + l15;
                int ch = (cbase + lq) ^ (n & 7);
                bfr[c] = *(const bf16x8*)&tB[n * BK + ch * 8];
            }
#pragma unroll
            for (int r = 0; r < RT; ++r)
#pragma unroll
                for (int c = 0; c < CT; ++c)
                    acc[r][c] = __builtin_amdgcn_mfma_f32_16x16x32_bf16(
                        af[r], bfr[c], acc[r][c], 0, 0, 0);
        }
    }

    // epilogue: C/D layout col = lane&15, row = (lane>>4)*4 + reg
    int nIdx[CT];
    int zb[CT];
#pragma unroll
    for (int c = 0; c < CT; ++c) {
        nIdx[c] = n0 + waveN + c * 16 + l15;
        if (SQMASK) zb[c] = ZB[nIdx[c]];
    }
#pragma unroll
    for (int r = 0; r < RT; ++r) {
        int mbase = m0 + waveM + r * 16 + lq * 4;
#pragma unroll
        for (int reg = 0; reg < 4; ++reg) {
            int m = mbase + reg;
            size_t rowoff = (size_t)m * (size_t)N;
            if (SQMASK) {
                int za = ZA[m];
                unsigned short* out = (unsigned short*)Cp;
#pragma unroll
                for (int c = 0; c < CT; ++c) {
                    float v = acc[r][c][reg];
                    float kv = (za == zb[c]) ? v * v : 0.0f;
                    out[rowoff + nIdx[c]] = f2bf(kv);
                }
            } else {
                float* out = (float*)Cp;
#pragma unroll
                for (int c = 0; c < CT; ++c)
                    out[rowoff + nIdx[c]] = acc[r][c][reg];
            }
        }
    }
}

extern "C" void kernel_launch(void* const* d_in, const int* in_sizes, int n_in,
                              void* d_out, int out_size, void* d_ws, size_t ws_size,
                              hipStream_t stream) {
    const float* Alpha = (const float*)d_in[0];   // [256, 4096]
    const float* X_ref = (const float*)d_in[1];   // [4096, 512]
    const float* desc  = (const float*)d_in[2];   // [8192, 512]
    const int*   Z_ref = (const int*)d_in[3];     // [4096]
    const int*   Z     = (const int*)d_in[4];     // [8192]
    float* out = (float*)d_out;                   // [256, 8192]

    // ws layout (bf16), total ~78 MB
    unsigned short* Xb = (unsigned short*)d_ws;            // 4096*512
    unsigned short* Db = Xb + (size_t)NREF * DF;           // 8192*512
    unsigned short* Ab = Db + (size_t)NIN * DF;            // 256*4096
    unsigned short* Kt = Ab + (size_t)P_DIM * NREF;        // 8192*4096 = K^T[j,i]

    cast_f32_bf16<<<1024, 256, 0, stream>>>(X_ref, Xb, NREF * DF / 4);
    cast_f32_bf16<<<1024, 256, 0, stream>>>(desc,  Db, NIN * DF / 4);
    cast_f32_bf16<<<1024, 256, 0, stream>>>(Alpha, Ab, P_DIM * NREF / 4);

    // GEMM1: Kt[j,i] = (Z[j]==Z_ref[i]) ? (desc_j . xref_i)^2 : 0
    // M=NIN(j), N=NREF(i), Kd=DF; A=desc_bf16, B=X_ref_bf16 (both K-contig)
    dim3 g1(NREF / 128, NIN / 128);   // (32, 64) = 2048 blocks
    gemm_bt<128, 128, 2, 2, true><<<g1, 256, 0, stream>>>(
        Db, Xb, (void*)Kt, Z, Z_ref, NIN, NREF, DF);

    // GEMM2: out[p,j] = sum_i Ab[p,i] * Kt[j,i]
    // M=P(p), N=NIN(j), Kd=NREF; A=Alpha_bf16, B=Kt (both K-contig)
    dim3 g2(NIN / 128, P_DIM / 64);   // (64, 4) = 256 blocks
    gemm_bt<64, 128, 2, 2, false><<<g2, 256, 0, stream>>>(
        Ab, Kt, (void*)out, nullptr, nullptr, P_DIM, NIN, NREF);
}

// Round 2
// 174.081 us; speedup vs baseline: 1.0921x; 1.0921x over previous
//
#include <hip/hip_runtime.h>
#include <stdint.h>

#define P_DIM 256
#define NREF  4096
#define NIN   8192
#define DF    512

typedef __bf16 bf16x8 __attribute__((ext_vector_type(8)));
typedef float  f32x4  __attribute__((ext_vector_type(4)));

static __device__ __forceinline__ unsigned short f2bf(float f) {
    uint32_t u = __builtin_bit_cast(uint32_t, f);
    u += 0x7FFFu + ((u >> 16) & 1u);
    return (unsigned short)(u >> 16);
}

// One kernel casts all three fp32 arrays to bf16 (vectorized x4).
__global__ void cast_all(const float* __restrict__ s0, unsigned short* __restrict__ d0, int n0,
                         const float* __restrict__ s1, unsigned short* __restrict__ d1, int n1,
                         const float* __restrict__ s2, unsigned short* __restrict__ d2, int n2) {
    int total = n0 + n1 + n2;
    int stride = gridDim.x * blockDim.x;
    for (int i = blockIdx.x * blockDim.x + threadIdx.x; i < total; i += stride) {
        const float4* s; ushort4* d; int j = i;
        if (j < n0) { s = (const float4*)s0; d = (ushort4*)d0; }
        else if ((j -= n0) < n1) { s = (const float4*)s1; d = (ushort4*)d1; }
        else { j -= n1; s = (const float4*)s2; d = (ushort4*)d2; }
        float4 v = s[j];
        ushort4 o;
        o.x = f2bf(v.x); o.y = f2bf(v.y); o.z = f2bf(v.z); o.w = f2bf(v.w);
        d[j] = o;
    }
}

__global__ void reduce_add(float* __restrict__ out, const float* __restrict__ part, int n4) {
    int i = blockIdx.x * blockDim.x + threadIdx.x;
    if (i < n4) {
        float4 a = ((const float4*)out)[i];
        float4 b = ((const float4*)part)[i];
        a.x += b.x; a.y += b.y; a.z += b.z; a.w += b.w;
        ((float4*)out)[i] = a;
    }
}

// C = A @ B^T, A[M,Kd], B[N,Kd] bf16 row-major (K-contiguous).
// SQMASK: C[m,n] = (ZA[m]==ZB[n]) ? dot^2 : 0, stored bf16.
// else:   C[m,n] = dot, fp32; blockIdx.z==0 -> C0, else C1 (split-K partial).
// BK=64 (128B rows); LDS 16B-chunk index XOR-swizzled by (row&7).
template <int BM, int BN, int WAVES, int WR, int WC, bool SQMASK>
__global__ __launch_bounds__(WAVES * 64) void gemm_bt(
    const unsigned short* __restrict__ A,
    const unsigned short* __restrict__ B,
    void* __restrict__ C0,
    void* __restrict__ C1,
    const int* __restrict__ ZA,
    const int* __restrict__ ZB,
    int M, int N, int KC)   // KC = K-elements per z-slice
{
    constexpr int BK = 64;
    constexpr int RT = BM / WR / 16;
    constexpr int CT = BN / WC / 16;
    __shared__ unsigned short tA[BM * BK];
    __shared__ unsigned short tB[BN * BK];

    const int tid  = threadIdx.x;
    const int wave = tid >> 6;
    const int lane = tid & 63;
    const int wr = wave / WC, wc = wave % WC;
    const int m0 = blockIdx.y * BM, n0 = blockIdx.x * BN;
    const int waveM = wr * (BM / WR), waveN = wc * (BN / WC);
    const int lrow = lane >> 3, ls = lane & 7;
    const int l15 = lane & 15, lq = lane >> 4;
    const size_t Kd = (size_t)KC * gridDim.z;   // full K stride of A/B rows
    const int kbeg = blockIdx.z * KC;

    f32x4 acc[RT][CT];
#pragma unroll
    for (int r = 0; r < RT; ++r)
#pragma unroll
        for (int c = 0; c < CT; ++c)
            acc[r][c] = (f32x4){0.f, 0.f, 0.f, 0.f};

    constexpr int TOTAL_CB = (BM + BN) / 8;
    constexpr int CB_PER_WAVE = TOTAL_CB / WAVES;
    static_assert(TOTAL_CB % WAVES == 0, "staging split");

    for (int k0 = kbeg; k0 < kbeg + KC; k0 += BK) {
        __syncthreads();
#pragma unroll
        for (int it = 0; it < CB_PER_WAVE; ++it) {
            int cb = wave + it * WAVES;
            bool isB = (cb >= BM / 8);
            int cb2 = isB ? cb - BM / 8 : cb;
            int row = cb2 * 8 + lrow;
            int g = ls ^ (row & 7);
            const unsigned short* gp = (isB ? B : A)
                + (size_t)((isB ? n0 : m0) + row) * Kd + (size_t)(k0 + g * 8);
            unsigned short* lp = (isB ? tB : tA) + cb2 * (8 * BK);
            __builtin_amdgcn_global_load_lds(
                (const __attribute__((address_space(1))) void*)gp,
                (__attribute__((address_space(3))) void*)lp,
                16, 0, 0);
        }
        __syncthreads();
#pragma unroll
        for (int kk = 0; kk < BK; kk += 32) {
            const int cbase = kk >> 3;
            bf16x8 af[RT], bfr[CT];
#pragma unroll
            for (int r = 0; r < RT; ++r) {
                int m = waveM + r * 16 + l15;
                int ch = (cbase + lq) ^ (m & 7);
                af[r] = *(const bf16x8*)&tA[m * BK + ch * 8];
            }
#pragma unroll
            for (int c = 0; c < CT; ++c) {
                int n = waveN + c * 16 + l15;
                int ch = (cbase + lq) ^ (n & 7);
                bfr[c] = *(const bf16x8*)&tB[n * BK + ch * 8];
            }
#pragma unroll
            for (int r = 0; r < RT; ++r)
#pragma unroll
                for (int c = 0; c < CT; ++c)
                    acc[r][c] = __builtin_amdgcn_mfma_f32_16x16x32_bf16(
                        af[r], bfr[c], acc[r][c], 0, 0, 0);
        }
    }

    // epilogue: C/D layout col = lane&15, row = (lane>>4)*4 + reg
    int nIdx[CT];
    int zb[CT];
#pragma unroll
    for (int c = 0; c < CT; ++c) {
        nIdx[c] = n0 + waveN + c * 16 + l15;
        if (SQMASK) zb[c] = ZB[nIdx[c]];
    }
    void* Cp = (blockIdx.z == 0) ? C0 : C1;
#pragma unroll
    for (int r = 0; r < RT; ++r) {
        int mbase = m0 + waveM + r * 16 + lq * 4;
#pragma unroll
        for (int reg = 0; reg < 4; ++reg) {
            int m = mbase + reg;
            size_t rowoff = (size_t)m * (size_t)N;
            if (SQMASK) {
                int za = ZA[m];
                unsigned short* out = (unsigned short*)Cp;
#pragma unroll
                for (int c = 0; c < CT; ++c) {
                    float v = acc[r][c][reg];
                    float kv = (za == zb[c]) ? v * v : 0.0f;
                    out[rowoff + nIdx[c]] = f2bf(kv);
                }
            } else {
                float* out = (float*)Cp;
#pragma unroll
                for (int c = 0; c < CT; ++c)
                    out[rowoff + nIdx[c]] = acc[r][c][reg];
            }
        }
    }
}

extern "C" void kernel_launch(void* const* d_in, const int* in_sizes, int n_in,
                              void* d_out, int out_size, void* d_ws, size_t ws_size,
                              hipStream_t stream) {
    const float* Alpha = (const float*)d_in[0];   // [256, 4096]
    const float* X_ref = (const float*)d_in[1];   // [4096, 512]
    const float* desc  = (const float*)d_in[2];   // [8192, 512]
    const int*   Z_ref = (const int*)d_in[3];     // [4096]
    const int*   Z     = (const int*)d_in[4];     // [8192]
    float* out = (float*)d_out;                   // [256, 8192]

    // ws layout (bf16), total 78 MB: Xb(4MB) Db(8MB) Ab(2MB) Kt(64MB)
    unsigned short* Xb = (unsigned short*)d_ws;            // 4096*512
    unsigned short* Db = Xb + (size_t)NREF * DF;           // 8192*512
    unsigned short* Ab = Db + (size_t)NIN * DF;            // 256*4096
    unsigned short* Kt = Ab + (size_t)P_DIM * NREF;        // 8192*4096 = K^T[j,i]
    // split-K partial (8 MB) reuses the Xb/Db region (dead after GEMM1)
    float* part = (float*)d_ws;

    cast_all<<<4096, 256, 0, stream>>>(
        X_ref, Xb, NREF * DF / 4,
        desc,  Db, NIN * DF / 4,
        Alpha, Ab, P_DIM * NREF / 4);

    // GEMM1: Kt[j,i] = (Z[j]==Z_ref[i]) ? (desc_j . xref_i)^2 : 0
    dim3 g1(NREF / 128, NIN / 128, 1);   // 2048 blocks
    gemm_bt<128, 128, 4, 2, 2, true><<<g1, 256, 0, stream>>>(
        Db, Xb, (void*)Kt, nullptr, Z, Z_ref, NIN, NREF, DF);

    // GEMM2: out[p,j] = sum_i Ab[p,i] * Kt[j,i]
    // BM=256 = full M (Kt read exactly once); BN=64; split-K=2
    dim3 g2(NIN / 64, 1, 2);             // 256 blocks, 512 threads
    gemm_bt<256, 64, 8, 4, 2, false><<<g2, 512, 0, stream>>>(
        Ab, Kt, (void*)out, (void*)part, nullptr, nullptr, P_DIM, NIN, NREF / 2);

    // out += partial
    reduce_add<<<(P_DIM * NIN / 4 + 255) / 256, 256, 0, stream>>>(
        out, part, P_DIM * NIN / 4);
}

// Round 3
// 164.605 us; speedup vs baseline: 1.1550x; 1.0576x over previous
//
#include <hip/hip_runtime.h>
#include <stdint.h>

#define P_DIM 256
#define NREF  4096
#define NIN   8192
#define DF    512

typedef __bf16 bf16x8 __attribute__((ext_vector_type(8)));
typedef float  f32x4  __attribute__((ext_vector_type(4)));

static __device__ __forceinline__ unsigned short f2bf(float f) {
    uint32_t u = __builtin_bit_cast(uint32_t, f);
    u += 0x7FFFu + ((u >> 16) & 1u);
    return (unsigned short)(u >> 16);
}
static __device__ __forceinline__ float bf2f(unsigned short u) {
    return __builtin_bit_cast(float, (uint32_t)u << 16);
}

// One kernel casts all three fp32 arrays to bf16 (vectorized x4).
__global__ void cast3(const float* __restrict__ s0, unsigned short* __restrict__ d0, int n0,
                      const float* __restrict__ s1, unsigned short* __restrict__ d1, int n1,
                      const float* __restrict__ s2, unsigned short* __restrict__ d2, int n2) {
    int total = n0 + n1 + n2;
    int stride = gridDim.x * blockDim.x;
    for (int i = blockIdx.x * blockDim.x + threadIdx.x; i < total; i += stride) {
        const float4* s; ushort4* d; int j = i;
        if (j < n0) { s = (const float4*)s0; d = (ushort4*)d0; }
        else if ((j -= n0) < n1) { s = (const float4*)s1; d = (ushort4*)d1; }
        else { j -= n1; s = (const float4*)s2; d = (ushort4*)d2; }
        float4 v = s[j];
        ushort4 o;
        o.x = f2bf(v.x); o.y = f2bf(v.y); o.z = f2bf(v.z); o.w = f2bf(v.w);
        d[j] = o;
    }
}

// out += sum of 3 bf16 partials (each PART elements)
__global__ void reduce3(float* __restrict__ out, const unsigned short* __restrict__ parts,
                        int n4, size_t partElems) {
    int i = blockIdx.x * blockDim.x + threadIdx.x;
    if (i >= n4) return;
    float4 a = ((const float4*)out)[i];
    const ushort4* p0 = (const ushort4*)(parts);
    const ushort4* p1 = (const ushort4*)(parts + partElems);
    const ushort4* p2 = (const ushort4*)(parts + 2 * partElems);
    ushort4 u0 = p0[i], u1 = p1[i], u2 = p2[i];
    a.x += bf2f(u0.x) + bf2f(u1.x) + bf2f(u2.x);
    a.y += bf2f(u0.y) + bf2f(u1.y) + bf2f(u2.y);
    a.z += bf2f(u0.z) + bf2f(u1.z) + bf2f(u2.z);
    a.w += bf2f(u0.w) + bf2f(u1.w) + bf2f(u2.w);
    ((float4*)out)[i] = a;
}

// C = A @ B^T, A[M,Kd], B[N,Kd] bf16 row-major (K-contiguous), Kd = KC*gridDim.z.
// SQMASK: C0[m,n] = (ZA[m]==ZB[n]) ? dot^2 : 0, stored bf16.
// else:   z==0 -> fp32 store to C0; z>0 -> bf16 partial to C1 + (z-1)*M*N.
// BK=64 (128B rows); LDS 16B-chunk index XOR-swizzled by (row&7).
template <int BM, int BN, int WAVES, int WR, int WC, bool SQMASK>
static __device__ __forceinline__ void gemm_body(
    const unsigned short* __restrict__ A,
    const unsigned short* __restrict__ B,
    void* __restrict__ C0,
    void* __restrict__ C1,
    const int* __restrict__ ZA,
    const int* __restrict__ ZB,
    int M, int N, int KC)
{
    constexpr int BK = 64;
    constexpr int RT = BM / WR / 16;
    constexpr int CT = BN / WC / 16;
    __shared__ unsigned short tA[BM * BK];
    __shared__ unsigned short tB[BN * BK];

    const int tid  = threadIdx.x;
    const int wave = tid >> 6;
    const int lane = tid & 63;
    const int wr = wave / WC, wc = wave % WC;
    const int m0 = blockIdx.y * BM, n0 = blockIdx.x * BN;
    const int waveM = wr * (BM / WR), waveN = wc * (BN / WC);
    const int lrow = lane >> 3, ls = lane & 7;
    const int l15 = lane & 15, lq = lane >> 4;
    const size_t Kd = (size_t)KC * gridDim.z;
    const int kbeg = blockIdx.z * KC;

    f32x4 acc[RT][CT];
#pragma unroll
    for (int r = 0; r < RT; ++r)
#pragma unroll
        for (int c = 0; c < CT; ++c)
            acc[r][c] = (f32x4){0.f, 0.f, 0.f, 0.f};

    constexpr int TOTAL_CB = (BM + BN) / 8;
    constexpr int CB_PER_WAVE = TOTAL_CB / WAVES;
    static_assert(TOTAL_CB % WAVES == 0, "staging split");

    for (int k0 = kbeg; k0 < kbeg + KC; k0 += BK) {
        __syncthreads();
#pragma unroll
        for (int it = 0; it < CB_PER_WAVE; ++it) {
            int cb = wave + it * WAVES;
            bool isB = (cb >= BM / 8);
            int cb2 = isB ? cb - BM / 8 : cb;
            int row = cb2 * 8 + lrow;
            int g = ls ^ (row & 7);
            const unsigned short* gp = (isB ? B : A)
                + (size_t)((isB ? n0 : m0) + row) * Kd + (size_t)(k0 + g * 8);
            unsigned short* lp = (isB ? tB : tA) + cb2 * (8 * BK);
            __builtin_amdgcn_global_load_lds(
                (const __attribute__((address_space(1))) void*)gp,
                (__attribute__((address_space(3))) void*)lp,
                16, 0, 0);
        }
        __syncthreads();
#pragma unroll
        for (int kk = 0; kk < BK; kk += 32) {
            const int cbase = kk >> 3;
            bf16x8 af[RT], bfr[CT];
#pragma unroll
            for (int r = 0; r < RT; ++r) {
                int m = waveM + r * 16 + l15;
                int ch = (cbase + lq) ^ (m & 7);
                af[r] = *(const bf16x8*)&tA[m * BK + ch * 8];
            }
#pragma unroll
            for (int c = 0; c < CT; ++c) {
                int n = waveN + c * 16 + l15;
                int ch = (cbase + lq) ^ (n & 7);
                bfr[c] = *(const bf16x8*)&tB[n * BK + ch * 8];
            }
#pragma unroll
            for (int r = 0; r < RT; ++r)
#pragma unroll
                for (int c = 0; c < CT; ++c)
                    acc[r][c] = __builtin_amdgcn_mfma_f32_16x16x32_bf16(
                        af[r], bfr[c], acc[r][c], 0, 0, 0);
        }
    }

    // epilogue: C/D layout col = lane&15, row = (lane>>4)*4 + reg
    int nIdx[CT];
    int zb[CT];
#pragma unroll
    for (int c = 0; c < CT; ++c) {
        nIdx[c] = n0 + waveN + c * 16 + l15;
        if (SQMASK) zb[c] = ZB[nIdx[c]];
    }
    const bool toPart = (!SQMASK) && (blockIdx.z != 0);
    unsigned short* partBase = (unsigned short*)C1
        + (size_t)(blockIdx.z ? blockIdx.z - 1 : 0) * (size_t)M * (size_t)N;
#pragma unroll
    for (int r = 0; r < RT; ++r) {
        int mbase = m0 + waveM + r * 16 + lq * 4;
#pragma unroll
        for (int reg = 0; reg < 4; ++reg) {
            int m = mbase + reg;
            size_t rowoff = (size_t)m * (size_t)N;
            if (SQMASK) {
                int za = ZA[m];
                unsigned short* outp = (unsigned short*)C0;
#pragma unroll
                for (int c = 0; c < CT; ++c) {
                    float v = acc[r][c][reg];
                    float kv = (za == zb[c]) ? v * v : 0.0f;
                    outp[rowoff + nIdx[c]] = f2bf(kv);
                }
            } else if (!toPart) {
                float* outp = (float*)C0;
#pragma unroll
                for (int c = 0; c < CT; ++c)
                    outp[rowoff + nIdx[c]] = acc[r][c][reg];
            } else {
#pragma unroll
                for (int c = 0; c < CT; ++c)
                    partBase[rowoff + nIdx[c]] = f2bf(acc[r][c][reg]);
            }
        }
    }
}

// Named wrappers so rocprof rows are distinguishable.
__global__ __launch_bounds__(256) void g1_desc_xref(
    const unsigned short* __restrict__ A, const unsigned short* __restrict__ B,
    void* __restrict__ C0, const int* __restrict__ ZA, const int* __restrict__ ZB,
    int M, int N, int KC) {
    gemm_body<128, 128, 4, 2, 2, true>(A, B, C0, nullptr, ZA, ZB, M, N, KC);
}

__global__ __launch_bounds__(256) void g2_alpha_kt(
    const unsigned short* __restrict__ A, const unsigned short* __restrict__ B,
    void* __restrict__ C0, void* __restrict__ C1,
    int M, int N, int KC) {
    gemm_body<128, 128, 4, 2, 2, false>(A, B, C0, C1, nullptr, nullptr, M, N, KC);
}

extern "C" void kernel_launch(void* const* d_in, const int* in_sizes, int n_in,
                              void* d_out, int out_size, void* d_ws, size_t ws_size,
                              hipStream_t stream) {
    const float* Alpha = (const float*)d_in[0];   // [256, 4096]
    const float* X_ref = (const float*)d_in[1];   // [4096, 512]
    const float* desc  = (const float*)d_in[2];   // [8192, 512]
    const int*   Z_ref = (const int*)d_in[3];     // [4096]
    const int*   Z     = (const int*)d_in[4];     // [8192]
    float* out = (float*)d_out;                   // [256, 8192]

    // ws layout (bf16), 78 MB total: Xb(4MB) Db(8MB) Ab(2MB) Kt(64MB)
    unsigned short* Xb = (unsigned short*)d_ws;            // 4096*512
    unsigned short* Db = Xb + (size_t)NREF * DF;           // 8192*512
    unsigned short* Ab = Db + (size_t)NIN * DF;            // 256*4096
    unsigned short* Kt = Ab + (size_t)P_DIM * NREF;        // 8192*4096 = K^T[j,i]
    // split-K bf16 partials (3 x 4MB) reuse the Xb/Db region (dead after GEMM1)
    unsigned short* part = (unsigned short*)d_ws;

    cast3<<<4096, 256, 0, stream>>>(
        X_ref, Xb, NREF * DF / 4,
        desc,  Db, NIN * DF / 4,
        Alpha, Ab, P_DIM * NREF / 4);

    // GEMM1: Kt[j,i] = (Z[j]==Z_ref[i]) ? (desc_j . xref_i)^2 : 0
    dim3 g1(NREF / 128, NIN / 128, 1);   // 2048 blocks
    g1_desc_xref<<<g1, 256, 0, stream>>>(
        Db, Xb, (void*)Kt, Z, Z_ref, NIN, NREF, DF);

    // GEMM2: out[p,j] = sum_i Ab[p,i] * Kt[j,i]
    // 128x128 tile (same ratio as GEMM1), split-K=4 -> 512 blocks = 2/CU.
    // z=0 -> fp32 into out; z=1..3 -> bf16 partials.
    dim3 g2(NIN / 128, P_DIM / 128, 4);  // (64,2,4) = 512 blocks
    g2_alpha_kt<<<g2, 256, 0, stream>>>(
        Ab, Kt, (void*)out, (void*)part, P_DIM, NIN, NREF / 4);

    // out += part0 + part1 + part2
    reduce3<<<(P_DIM * NIN / 4 + 255) / 256, 256, 0, stream>>>(
        out, part, P_DIM * NIN / 4, (size_t)P_DIM * NIN);
}